// Round 3
// baseline (473.586 us; speedup 1.0000x reference)
//
#include <hip/hip_runtime.h>
#include <hip/hip_bf16.h>

// ContrastiveLoss on MI355X — round 3.
// loss = -mean_i (1/P_i) * sum_{j: y_ij=1} [ s_ij - log(exp(s_ij) + nl_i) ]
// Approximations (error budget ~1.5e-4 on loss ~10.5, threshold 0.21):
//   off-diag positives: log(e + nl) ~= log(nl)   (mean e/nl ~ 1.2e-4)
//   diagonal handled exactly via stored s_ii.
// Per-row quantities accumulated in one pass over S:
//   T  = sum_{j != i} e_ij          (dense)
//   A  = sum_{j != i, y=1} s_ij
//   Y1 = sum_{j != i, y=1} e_ij     ->  nl = T - Y1
//   P  = popcount(y-bits row)       (free, in finalize)
// R3 structure: y compressed to bits by a streaming pre-pass (256MB at pure
// stream BW); main kernel computes the S-tile TRANSPOSED (swap MFMA operands)
// so row-sums need only 2 shfl_xor; no LDS/syncthreads in main kernel.

#define NN 8192

typedef short bf16x8 __attribute__((ext_vector_type(8)));
typedef float f32x4 __attribute__((ext_vector_type(4)));
typedef unsigned long long u64;
typedef unsigned int u32;

__device__ inline unsigned short f32_to_bf16_rne(float f) {
    unsigned u = __float_as_uint(f);
    unsigned r = 0x7FFFu + ((u >> 16) & 1u);
    return (unsigned short)((u + r) >> 16);
}

// ---- kernel 1: fused {L2-normalize+cast} and {y -> bitmask} ----
// blocks [0,2048): one wave per row, normalize x and cast to bf16.
// blocks [2048,4096): streaming ballot compress of y (256 MB -> 8 MB).
__global__ __launch_bounds__(256) void prep_kernel(
    const float* __restrict__ x, const float* __restrict__ y,
    unsigned short* __restrict__ xn, u64* __restrict__ bits) {
    const int t = threadIdx.x;
    const int w = t >> 6, l = t & 63;
    if (blockIdx.x < 2048) {
        const int row = blockIdx.x * 4 + w;
        float2 v = reinterpret_cast<const float2*>(x)[row * 64 + l];
        float ss = v.x * v.x + v.y * v.y;
#pragma unroll
        for (int m = 1; m < 64; m <<= 1) ss += __shfl_xor(ss, m);
        float rn = 1.0f / sqrtf(ss);
        ushort2 st;
        st.x = f32_to_bf16_rne(v.x * rn);
        st.y = f32_to_bf16_rne(v.y * rn);
        reinterpret_cast<ushort2*>(xn)[row * 64 + l] = st;
    } else {
        const int gw = (blockIdx.x - 2048) * 4 + w;  // 0..8191
#pragma unroll 1
        for (int it = 0; it < 32; ++it) {
            const size_t w0 = ((size_t)it * 8192 + gw) * 4;
            u64 m0 = __ballot(y[(w0 + 0) * 64 + l] != 0.0f);
            u64 m1 = __ballot(y[(w0 + 1) * 64 + l] != 0.0f);
            u64 m2 = __ballot(y[(w0 + 2) * 64 + l] != 0.0f);
            u64 m3 = __ballot(y[(w0 + 3) * 64 + l] != 0.0f);
            if (l == 0) {
                bits[w0 + 0] = m0;
                bits[w0 + 1] = m1;
                bits[w0 + 2] = m2;
                bits[w0 + 3] = m3;
            }
        }
    }
}

// Epilogue: per lane, values acc[p][qq][j] sit at S-col c = C0+p*16+lh*4+j,
// S-row r = R0+qq*16+lm16 (transposed-tile layout). Row sums need only
// in-lane adds + shfl_xor(16,32).
template <bool DIAG>
__device__ __forceinline__ void epilogue(
    const f32x4 (&acc)[4][4], const u64 (&bw)[4], int l, int lm16, int lh4,
    int wM, int wN, int R0, int cb, float* __restrict__ Pt,
    float* __restrict__ sdg) {
#pragma unroll
    for (int qq = 0; qq < 4; ++qq) {
        float T = 0.0f, A = 0.0f, Y = 0.0f;
        const u32 lo = (u32)bw[qq];
        const u32 hi = (u32)(bw[qq] >> 32);
        const int rl = qq * 16 + lm16;  // row pos within wave's 64-col range
#pragma unroll
        for (int p = 0; p < 4; ++p) {
            const u32 wsel = (p < 2) ? lo : hi;
#pragma unroll
            for (int j = 0; j < 4; ++j) {
                float s = 20.0f * acc[p][qq][j];
                float e = __expf(s);
                float yv = (float)((wsel >> ((p & 1) * 16 + lh4 + j)) & 1u);
                if (DIAG) {
                    if (wM == wN && (p * 16 + lh4 + j) == rl) {
                        sdg[R0 + rl] = s;
                        e = 0.0f;
                        yv = 0.0f;
                    }
                }
                T += e;
                A = fmaf(yv, s, A);
                Y = fmaf(yv, e, Y);
            }
        }
        T += __shfl_xor(T, 16); T += __shfl_xor(T, 32);
        A += __shfl_xor(A, 16); A += __shfl_xor(A, 32);
        Y += __shfl_xor(Y, 16); Y += __shfl_xor(Y, 32);
        if (l < 16) {
            const size_t idx = (size_t)(cb * 2 + wM) * NN + (R0 + qq * 16 + l);
            Pt[idx] = T;
            Pt[1048576 + idx] = A;
            Pt[2 * 1048576 + idx] = Y;
        }
    }
}

// ---- kernel 2: transposed S-tile MFMA + in-register row accumulation ----
__global__ __launch_bounds__(256, 3) void contrast_main_kernel(
    const unsigned short* __restrict__ xn, const u64* __restrict__ bits,
    float* __restrict__ Pt, float* __restrict__ sdg) {
    const int cb = blockIdx.x, rb = blockIdx.y;
    const int t = threadIdx.x;
    const int w = t >> 6, l = t & 63;
    const int wM = w >> 1, wN = w & 1;  // wM: col-half, wN: row-half
    const int lm16 = l & 15, lh = l >> 4, lh4 = lh << 2;

    const int C0 = cb * 128 + wM * 64;  // S-col base for this wave
    const int R0 = rb * 128 + wN * 64;  // S-row base for this wave

    // ---- bits: 1 u64 per row-frag per lane (broadcast across 4 lh groups)
    u64 bw[4];
#pragma unroll
    for (int qq = 0; qq < 4; ++qq)
        bw[qq] = bits[(size_t)(R0 + qq * 16 + lm16) * 128 + cb * 2 + wM];

    // ---- MFMA, transposed tile: A-operand <- S-col panel, B <- S-row panel
    f32x4 acc[4][4];
#pragma unroll
    for (int i = 0; i < 4; ++i)
#pragma unroll
        for (int j = 0; j < 4; ++j) {
            f32x4 z = {0.0f, 0.0f, 0.0f, 0.0f};
            acc[i][j] = z;
        }

    const char* xb = reinterpret_cast<const char*>(xn);
#pragma unroll
    for (int ks = 0; ks < 4; ++ks) {
        bf16x8 af[4], bfr[4];
#pragma unroll
        for (int p = 0; p < 4; ++p) {
            const size_t c = (size_t)(C0 + p * 16 + lm16);
            af[p] = *reinterpret_cast<const bf16x8*>(xb + c * 256 + ks * 64 +
                                                     lh * 16);
        }
#pragma unroll
        for (int qq = 0; qq < 4; ++qq) {
            const size_t r = (size_t)(R0 + qq * 16 + lm16);
            bfr[qq] = *reinterpret_cast<const bf16x8*>(xb + r * 256 + ks * 64 +
                                                       lh * 16);
        }
#pragma unroll
        for (int p = 0; p < 4; ++p)
#pragma unroll
            for (int qq = 0; qq < 4; ++qq)
                acc[p][qq] = __builtin_amdgcn_mfma_f32_16x16x32_bf16(
                    af[p], bfr[qq], acc[p][qq], 0, 0, 0);
    }

    if (cb == rb)
        epilogue<true>(acc, bw, l, lm16, lh4, wM, wN, R0, cb, Pt, sdg);
    else
        epilogue<false>(acc, bw, l, lm16, lh4, wM, wN, R0, cb, Pt, sdg);
}

// ---- kernel 3: reduce 128 slices per row, popcount P, assemble loss ----
__global__ __launch_bounds__(256) void finalize_kernel(
    const float* __restrict__ Pt, const u64* __restrict__ bits,
    const float* __restrict__ sdg, float* __restrict__ out) {
    const int t = threadIdx.x;
    const int w = t >> 6, l = t & 63;
    const int r = blockIdx.x * 4 + w;

    const size_t base = (size_t)l * NN + r;
    float T = Pt[base] + Pt[base + (size_t)64 * NN];
    float A = Pt[1048576 + base] + Pt[1048576 + base + (size_t)64 * NN];
    float Y = Pt[2 * 1048576 + base] + Pt[2 * 1048576 + base + (size_t)64 * NN];
    u64 b0 = bits[(size_t)r * 128 + l];
    u64 b1 = bits[(size_t)r * 128 + 64 + l];
    float Pc = (float)(__popcll(b0) + __popcll(b1));
#pragma unroll
    for (int m = 1; m < 64; m <<= 1) {
        T += __shfl_xor(T, m);
        A += __shfl_xor(A, m);
        Y += __shfl_xor(Y, m);
        Pc += __shfl_xor(Pc, m);
    }

    __shared__ float red[4];
    if (l == 0) {
        const float nl = T - Y;
        const float sd = sdg[r];
        // lm = [ A_off - (P-1) ln(nl) + sm_diag ] / P,  sm_diag = -log1p(nl e^-sd)
        red[w] = (A - (Pc - 1.0f) * logf(nl) - log1pf(nl * __expf(-sd))) / Pc;
    }
    __syncthreads();
    if (t == 0) {
        float s = red[0] + red[1] + red[2] + red[3];
        atomicAdd(out, -s * (1.0f / (float)NN));
    }
}

extern "C" void kernel_launch(void* const* d_in, const int* in_sizes, int n_in,
                              void* d_out, int out_size, void* d_ws,
                              size_t ws_size, hipStream_t stream) {
    const float* x = (const float*)d_in[0];
    const float* y = (const float*)d_in[1];

    char* ws = (char*)d_ws;
    unsigned short* xn = (unsigned short*)ws;       // 2 MB
    u64* bits = (u64*)(ws + (2ull << 20));          // 8 MB  (8192 x 128 u64)
    float* Pt = (float*)(ws + (10ull << 20));       // 12 MB (3 x 128 x 8192)
    float* sdg = (float*)(ws + (22ull << 20));      // 32 KB

    hipMemsetAsync(d_out, 0, sizeof(float), stream);
    prep_kernel<<<4096, 256, 0, stream>>>(x, y, xn, bits);
    contrast_main_kernel<<<dim3(64, 64), 256, 0, stream>>>(xn, bits, Pt, sdg);
    finalize_kernel<<<NN / 4, 256, 0, stream>>>(Pt, bits, sdg, (float*)d_out);
}

// Round 4
// 411.366 us; speedup vs baseline: 1.1513x; 1.1513x over previous
//
#include <hip/hip_runtime.h>
#include <hip/hip_bf16.h>

// ContrastiveLoss on MI355X — round 4.
// loss = -mean_i (1/P_i) * sum_{j: y_ij=1} [ s_ij - log(exp(s_ij) + nl_i) ]
// Approx (validated R3, absmax 0.0): off-diag positives log(e+nl) ~= log(nl);
// diagonal exact via stored s_ii. Per-row: T = sum_{j!=i} e, A = sum_y s,
// Y = sum_y e (off-diag), nl = T - Y, P = popcount(bits row).
//
// R4 vs R3 (474us; est. kernels ~224us after ~250us fixed replay overhead):
//  - main: LDS-staged panels (R1-verified global_load_lds linear-dest +
//    XOR-swizzle src/read pair) instead of 16-line-scatter L2 fragment loads;
//    512-thr blocks, 2 blk/CU (16 waves/CU); XCD-swizzled block ids.
//  - prep: float4 y loads (16B/lane) with ballot-native interleaved bit
//    layout; main extracts bits with 2 VALU/value.
//  - finalize: Pt transposed to [row][slice] -> fully coalesced; rowloss +
//    1-block reduce (no atomics).

#define NN 8192

typedef short bf16x8 __attribute__((ext_vector_type(8)));
typedef float f32x4 __attribute__((ext_vector_type(4)));
typedef unsigned long long u64;
typedef unsigned int u32;

__device__ inline unsigned short f32_to_bf16_rne(float f) {
    unsigned u = __float_as_uint(f);
    unsigned r = 0x7FFFu + ((u >> 16) & 1u);
    return (unsigned short)((u + r) >> 16);
}

// ---- kernel 1: {L2-normalize+cast x} and {y -> interleaved bitmask} ----
// bits layout: word(r, g, e), g = col>>8, e = col&3; bit l = y[r, g*256+l*4+e]
__global__ __launch_bounds__(256) void prep_kernel(
    const float* __restrict__ x, const float* __restrict__ y,
    unsigned short* __restrict__ xn, u64* __restrict__ bits) {
    const int t = threadIdx.x;
    const int w = t >> 6, l = t & 63;
    if (blockIdx.x < 2048) {
        const int row = blockIdx.x * 4 + w;
        float2 v = reinterpret_cast<const float2*>(x)[row * 64 + l];
        float ss = v.x * v.x + v.y * v.y;
#pragma unroll
        for (int m = 1; m < 64; m <<= 1) ss += __shfl_xor(ss, m);
        float rn = 1.0f / sqrtf(ss);
        ushort2 st;
        st.x = f32_to_bf16_rne(v.x * rn);
        st.y = f32_to_bf16_rne(v.y * rn);
        reinterpret_cast<ushort2*>(xn)[row * 64 + l] = st;
    } else {
        const int r = (blockIdx.x - 2048) * 4 + w;  // one row per wave
        const float4* yr =
            reinterpret_cast<const float4*>(y + (size_t)r * NN);
        u64* br = bits + (size_t)r * 128;
#pragma unroll 4
        for (int g = 0; g < 32; ++g) {
            float4 v = yr[g * 64 + l];  // 1 KB/wave coalesced
            u64 m0 = __ballot(v.x != 0.0f);
            u64 m1 = __ballot(v.y != 0.0f);
            u64 m2 = __ballot(v.z != 0.0f);
            u64 m3 = __ballot(v.w != 0.0f);
            if (l == 0) {
                br[g * 4 + 0] = m0;
                br[g * 4 + 1] = m1;
                br[g * 4 + 2] = m2;
                br[g * 4 + 3] = m3;
            }
        }
    }
}

// ---- epilogue helper (templated on diagonal-block) ----
template <bool DIAG>
__device__ __forceinline__ void epilogue(
    const f32x4 (&acc)[4][2], const u32 (&W0)[4], const u32 (&W1)[4],
    int shbase, int wM, int wN, int lm16, int lh, int l, int rb, int cb,
    float* __restrict__ PtT, float* __restrict__ PtA, float* __restrict__ PtY,
    float* __restrict__ sdg) {
#pragma unroll
    for (int qq = 0; qq < 2; ++qq) {
        float T = 0.0f, A = 0.0f, Y = 0.0f;
        const int rl = wN * 32 + qq * 16 + lm16;  // row pos in 128-tile
#pragma unroll
        for (int p = 0; p < 4; ++p) {
            const int cl = wM * 64 + p * 16 + lh * 4;  // col pos base in tile
#pragma unroll
            for (int j = 0; j < 4; ++j) {
                float s = 20.0f * acc[p][qq][j];
                float e = __expf(s);
                u32 word = qq ? W1[j] : W0[j];
                u32 bit = (word >> (shbase + p * 4)) & 1u;
                if (DIAG) {
                    if (cl + j == rl) {
                        sdg[rb * 128 + rl] = s;
                        e = 0.0f;
                        bit = 0u;
                    }
                }
                T += e;
                A += bit ? s : 0.0f;
                Y += bit ? e : 0.0f;
            }
        }
        T += __shfl_xor(T, 16); T += __shfl_xor(T, 32);
        A += __shfl_xor(A, 16); A += __shfl_xor(A, 32);
        Y += __shfl_xor(Y, 16); Y += __shfl_xor(Y, 32);
        if (l < 16) {
            const size_t idx =
                (size_t)(rb * 128 + wN * 32 + qq * 16 + l) * 128 + cb * 2 + wM;
            PtT[idx] = T;
            PtA[idx] = A;
            PtY[idx] = Y;
        }
    }
}

// ---- kernel 2: LDS-staged transposed S-tile MFMA + row accumulation ----
__global__ __launch_bounds__(512, 4) void contrast_main_kernel(
    const unsigned short* __restrict__ xn, const u64* __restrict__ bits,
    float* __restrict__ PtT, float* __restrict__ PtA, float* __restrict__ PtY,
    float* __restrict__ sdg) {
    __shared__ __align__(1024) char lds[65536];  // [0,32K) cols | [32K,64K) rows

    const int bid = blockIdx.x;
    const int swz = (bid & 7) * 512 + (bid >> 3);  // bijective XCD swizzle
    const int cb = swz & 63, rb = swz >> 6;
    const int t = threadIdx.x;
    const int w = t >> 6, l = t & 63;
    const int wM = w & 1, wN = w >> 1;  // col half / row quarter
    const int lm16 = l & 15, lh = l >> 4;

    // ---- bits words for this wave's 32 rows x 64-col range (issued first)
    const int g4 = (cb >> 1) * 4;
    const int rbase = rb * 128 + wN * 32;
    u64 B0[4], B1[4];
    {
        const u64* bp0 = bits + (size_t)(rbase + lm16) * 128 + g4;
        const u64* bp1 = bits + (size_t)(rbase + 16 + lm16) * 128 + g4;
        ulonglong2 a0 = *reinterpret_cast<const ulonglong2*>(bp0);
        ulonglong2 a1 = *reinterpret_cast<const ulonglong2*>(bp0 + 2);
        ulonglong2 c0 = *reinterpret_cast<const ulonglong2*>(bp1);
        ulonglong2 c1 = *reinterpret_cast<const ulonglong2*>(bp1 + 2);
        B0[0] = a0.x; B0[1] = a0.y; B0[2] = a1.x; B0[3] = a1.y;
        B1[0] = c0.x; B1[1] = c0.y; B1[2] = c1.x; B1[3] = c1.y;
    }
    const int base = (cb & 1) * 32 + wM * 16;  // wave-uniform; no 32-straddle
    const bool hi = base >= 32;
    u32 W0[4], W1[4];
#pragma unroll
    for (int e = 0; e < 4; ++e) {
        W0[e] = hi ? (u32)(B0[e] >> 32) : (u32)B0[e];
        W1[e] = hi ? (u32)(B1[e] >> 32) : (u32)B1[e];
    }
    const int shbase = (base & 31) + lh;

    // ---- stage both panels: linear LDS dest + inverse-swizzled global src
    {
        const char* xb = reinterpret_cast<const char*>(xn);
        const char* srcA = xb + (size_t)cb * 32768;
        const char* srcB = xb + (size_t)rb * 32768;
#pragma unroll
        for (int i = 0; i < 8; ++i) {
            const int p = i * 8192 + t * 16;
            const int pp = p & 32767;
            const int src = pp ^ (((pp >> 8) & 7) << 4);
            __builtin_amdgcn_global_load_lds(
                (const __attribute__((address_space(1))) void*)(
                    (i < 4 ? srcA : srcB) + src),
                (__attribute__((address_space(3))) void*)(lds + p), 16, 0, 0);
        }
    }
    asm volatile("s_waitcnt vmcnt(0)" ::: "memory");
    __syncthreads();

    // ---- MFMA: per wave 64 cols (p) x 32 rows (qq), transposed-tile layout
    f32x4 acc[4][2];
#pragma unroll
    for (int i = 0; i < 4; ++i)
#pragma unroll
        for (int j = 0; j < 2; ++j) {
            f32x4 z = {0.0f, 0.0f, 0.0f, 0.0f};
            acc[i][j] = z;
        }

#pragma unroll
    for (int ks = 0; ks < 4; ++ks) {
        bf16x8 af[4], bfr[2];
#pragma unroll
        for (int p = 0; p < 4; ++p) {
            const int c = wM * 64 + p * 16 + lm16;
            const int v = c * 256 + ks * 64 + lh * 16;
            af[p] = *reinterpret_cast<const bf16x8*>(lds + (v ^ ((c & 7) << 4)));
        }
#pragma unroll
        for (int qq = 0; qq < 2; ++qq) {
            const int r = wN * 32 + qq * 16 + lm16;
            const int v = r * 256 + ks * 64 + lh * 16;
            bfr[qq] = *reinterpret_cast<const bf16x8*>(
                lds + 32768 + (v ^ ((r & 7) << 4)));
        }
#pragma unroll
        for (int p = 0; p < 4; ++p)
#pragma unroll
            for (int qq = 0; qq < 2; ++qq)
                acc[p][qq] = __builtin_amdgcn_mfma_f32_16x16x32_bf16(
                    af[p], bfr[qq], acc[p][qq], 0, 0, 0);
    }

    if (rb == cb)
        epilogue<true>(acc, W0, W1, shbase, wM, wN, lm16, lh, l, rb, cb, PtT,
                       PtA, PtY, sdg);
    else
        epilogue<false>(acc, W0, W1, shbase, wM, wN, lm16, lh, l, rb, cb, PtT,
                        PtA, PtY, sdg);
}

// ---- kernel 3: per-row reduce (coalesced) + row loss ----
__global__ __launch_bounds__(1024) void finalize_kernel(
    const float* __restrict__ PtT, const float* __restrict__ PtA,
    const float* __restrict__ PtY, const u64* __restrict__ bits,
    const float* __restrict__ sdg, float* __restrict__ rowloss) {
    const int t = threadIdx.x;
    const int w = t >> 6, l = t & 63;
    const int r = blockIdx.x * 16 + w;  // one wave per row

    float2 vT = reinterpret_cast<const float2*>(PtT + (size_t)r * 128)[l];
    float2 vA = reinterpret_cast<const float2*>(PtA + (size_t)r * 128)[l];
    float2 vY = reinterpret_cast<const float2*>(PtY + (size_t)r * 128)[l];
    ulonglong2 bb =
        reinterpret_cast<const ulonglong2*>(bits + (size_t)r * 128)[l];
    float T = vT.x + vT.y, A = vA.x + vA.y, Y = vY.x + vY.y;
    float P = (float)(__popcll(bb.x) + __popcll(bb.y));
#pragma unroll
    for (int m = 1; m < 64; m <<= 1) {
        T += __shfl_xor(T, m);
        A += __shfl_xor(A, m);
        Y += __shfl_xor(Y, m);
        P += __shfl_xor(P, m);
    }
    if (l == 0) {
        const float nl = T - Y;
        rowloss[r] =
            (A - (P - 1.0f) * logf(nl) - log1pf(nl * __expf(-sdg[r]))) / P;
    }
}

// ---- kernel 4: final mean ----
__global__ void reduce_kernel(const float* __restrict__ rowloss,
                              float* __restrict__ out) {
    __shared__ float red[256];
    const int t = threadIdx.x;
    float s = 0.0f;
#pragma unroll
    for (int i = 0; i < 8; ++i) {
        float4 v = reinterpret_cast<const float4*>(rowloss)[i * 256 + t];
        s += v.x + v.y + v.z + v.w;
    }
    red[t] = s;
    __syncthreads();
    for (int k = 128; k > 0; k >>= 1) {
        if (t < k) red[t] += red[t + k];
        __syncthreads();
    }
    if (t == 0) out[0] = -red[0] / (float)NN;
}

extern "C" void kernel_launch(void* const* d_in, const int* in_sizes, int n_in,
                              void* d_out, int out_size, void* d_ws,
                              size_t ws_size, hipStream_t stream) {
    const float* x = (const float*)d_in[0];
    const float* y = (const float*)d_in[1];

    char* ws = (char*)d_ws;
    unsigned short* xn = (unsigned short*)ws;          // 2 MB
    u64* bits = (u64*)(ws + (2ull << 20));             // 8 MB
    float* PtT = (float*)(ws + (10ull << 20));         // 4 MB  [row][slice]
    float* PtA = (float*)(ws + (14ull << 20));         // 4 MB
    float* PtY = (float*)(ws + (18ull << 20));         // 4 MB
    float* sdg = (float*)(ws + (22ull << 20));         // 32 KB
    float* rowloss = (float*)(ws + (22ull << 20) + 32768);  // 32 KB

    prep_kernel<<<4096, 256, 0, stream>>>(x, y, xn, bits);
    contrast_main_kernel<<<4096, 512, 0, stream>>>(xn, bits, PtT, PtA, PtY,
                                                   sdg);
    finalize_kernel<<<512, 1024, 0, stream>>>(PtT, PtA, PtY, bits, sdg,
                                              rowloss);
    reduce_kernel<<<1, 256, 0, stream>>>(rowloss, (float*)d_out);
}

// Round 5
// 410.887 us; speedup vs baseline: 1.1526x; 1.0012x over previous
//
#include <hip/hip_runtime.h>
#include <hip/hip_bf16.h>

// ContrastiveLoss on MI355X — round 5.
// loss = -mean_i (1/P_i) * sum_{j: y_ij=1} [ s_ij - log(exp(s_ij) + nl_i) ]
// Approx (validated R3/R4, absmax 0.0): off-diag positives log(e+nl) ~= log(nl);
// diagonal exact with s_ii = 20 (cos_ii = 1 in fp32 -> constant, sdg removed).
// Per-row: T = sum_{j!=i} e, A = sum_y s (off-diag), Y = sum_y e (off-diag),
// nl = T - Y, P = popcount(y row) (computed in prep).
//
// R5 vs R4 (411us; ~250us fixed fill/restore overhead + ~160us kernels):
//  - main: per-block LDS combine -> Pt[slice=cb][row] with fully coalesced
//    512B stores (was 16-lane x 512B-stride 4B scatters, ~16x write amp).
//  - finalize: thread-per-row slice loop, all loads coalesced, no shuffles;
//    P from prep popcount; final mean folded in (reduce kernel removed).
//  - diag handled as constant s_ii=20 -> sdg array/store/branch removed.

#define NN 8192

typedef short bf16x8 __attribute__((ext_vector_type(8)));
typedef float f32x4 __attribute__((ext_vector_type(4)));
typedef unsigned long long u64;
typedef unsigned int u32;

__device__ inline unsigned short f32_to_bf16_rne(float f) {
    unsigned u = __float_as_uint(f);
    unsigned r = 0x7FFFu + ((u >> 16) & 1u);
    return (unsigned short)((u + r) >> 16);
}

// ---- kernel 1: {L2-normalize+cast x} and {y -> interleaved bitmask + P} ----
// bits layout: word(r, g, e), g = col>>8, e = col&3; bit l = y[r, g*256+l*4+e]
__global__ __launch_bounds__(256) void prep_kernel(
    const float* __restrict__ x, const float* __restrict__ y,
    unsigned short* __restrict__ xn, u64* __restrict__ bits,
    float* __restrict__ Pp) {
    const int t = threadIdx.x;
    const int w = t >> 6, l = t & 63;
    if (blockIdx.x < 2048) {
        const int row = blockIdx.x * 4 + w;
        float2 v = reinterpret_cast<const float2*>(x)[row * 64 + l];
        float ss = v.x * v.x + v.y * v.y;
#pragma unroll
        for (int m = 1; m < 64; m <<= 1) ss += __shfl_xor(ss, m);
        float rn = 1.0f / sqrtf(ss);
        ushort2 st;
        st.x = f32_to_bf16_rne(v.x * rn);
        st.y = f32_to_bf16_rne(v.y * rn);
        reinterpret_cast<ushort2*>(xn)[row * 64 + l] = st;
    } else {
        const int r = (blockIdx.x - 2048) * 4 + w;  // one row per wave
        const float4* yr =
            reinterpret_cast<const float4*>(y + (size_t)r * NN);
        u64* br = bits + (size_t)r * 128;
        int pc = 0;
#pragma unroll 4
        for (int g = 0; g < 32; ++g) {
            float4 v = yr[g * 64 + l];  // 1 KB/wave coalesced
            u64 m0 = __ballot(v.x != 0.0f);
            u64 m1 = __ballot(v.y != 0.0f);
            u64 m2 = __ballot(v.z != 0.0f);
            u64 m3 = __ballot(v.w != 0.0f);
            pc += __popcll(m0) + __popcll(m1) + __popcll(m2) + __popcll(m3);
            if (l == 0) {
                br[g * 4 + 0] = m0;
                br[g * 4 + 1] = m1;
                br[g * 4 + 2] = m2;
                br[g * 4 + 3] = m3;
            }
        }
        if (l == 0) Pp[r] = (float)pc;
    }
}

// ---- epilogue helper (templated on diagonal-block) ----
template <bool DIAG>
__device__ __forceinline__ void epilogue(
    const f32x4 (&acc)[4][2], const u32 (&W0)[4], const u32 (&W1)[4],
    int shbase, int wM, int wN, int lm16, int lh, int l,
    float* __restrict__ Lb) {
#pragma unroll
    for (int qq = 0; qq < 2; ++qq) {
        float T = 0.0f, A = 0.0f, Y = 0.0f;
        const int rl = wN * 32 + qq * 16 + lm16;  // row pos in 128-tile
#pragma unroll
        for (int p = 0; p < 4; ++p) {
            const int cl = wM * 64 + p * 16 + lh * 4;  // col pos base in tile
#pragma unroll
            for (int j = 0; j < 4; ++j) {
                float s = 20.0f * acc[p][qq][j];
                float e = __expf(s);
                u32 word = qq ? W1[j] : W0[j];
                u32 bit = (word >> (shbase + p * 4)) & 1u;
                if (DIAG) {
                    if (cl + j == rl) {  // exclude diagonal from T/A/Y
                        e = 0.0f;
                        bit = 0u;
                    }
                }
                T += e;
                A += bit ? s : 0.0f;
                Y += bit ? e : 0.0f;
            }
        }
        T += __shfl_xor(T, 16); T += __shfl_xor(T, 32);
        A += __shfl_xor(A, 16); A += __shfl_xor(A, 32);
        Y += __shfl_xor(Y, 16); Y += __shfl_xor(Y, 32);
        if (l < 16) {
            const int r = wN * 32 + qq * 16 + l;
            Lb[(wM * 3 + 0) * 128 + r] = T;
            Lb[(wM * 3 + 1) * 128 + r] = A;
            Lb[(wM * 3 + 2) * 128 + r] = Y;
        }
    }
}

// ---- kernel 2: LDS-staged transposed S-tile MFMA + row accumulation ----
__global__ __launch_bounds__(512, 4) void contrast_main_kernel(
    const unsigned short* __restrict__ xn, const u64* __restrict__ bits,
    float* __restrict__ PtT, float* __restrict__ PtA,
    float* __restrict__ PtY) {
    __shared__ __align__(1024) char lds[68608];  // 64K panels | 3K combine
    float* Lb = reinterpret_cast<float*>(lds + 65536);

    const int bid = blockIdx.x;
    const int swz = (bid & 7) * 512 + (bid >> 3);  // bijective XCD swizzle
    const int cb = swz & 63, rb = swz >> 6;
    const int t = threadIdx.x;
    const int w = t >> 6, l = t & 63;
    const int wM = w & 1, wN = w >> 1;  // col half / row quarter
    const int lm16 = l & 15, lh = l >> 4;

    // ---- bits words for this wave's 32 rows x 64-col range (issued first)
    const int g4 = (cb >> 1) * 4;
    const int rbase = rb * 128 + wN * 32;
    u64 B0[4], B1[4];
    {
        const u64* bp0 = bits + (size_t)(rbase + lm16) * 128 + g4;
        const u64* bp1 = bits + (size_t)(rbase + 16 + lm16) * 128 + g4;
        ulonglong2 a0 = *reinterpret_cast<const ulonglong2*>(bp0);
        ulonglong2 a1 = *reinterpret_cast<const ulonglong2*>(bp0 + 2);
        ulonglong2 c0 = *reinterpret_cast<const ulonglong2*>(bp1);
        ulonglong2 c1 = *reinterpret_cast<const ulonglong2*>(bp1 + 2);
        B0[0] = a0.x; B0[1] = a0.y; B0[2] = a1.x; B0[3] = a1.y;
        B1[0] = c0.x; B1[1] = c0.y; B1[2] = c1.x; B1[3] = c1.y;
    }
    const int base = (cb & 1) * 32 + wM * 16;  // wave-uniform; no 32-straddle
    const bool hi = base >= 32;
    u32 W0[4], W1[4];
#pragma unroll
    for (int e = 0; e < 4; ++e) {
        W0[e] = hi ? (u32)(B0[e] >> 32) : (u32)B0[e];
        W1[e] = hi ? (u32)(B1[e] >> 32) : (u32)B1[e];
    }
    const int shbase = (base & 31) + lh;

    // ---- stage both panels: linear LDS dest + inverse-swizzled global src
    {
        const char* xb = reinterpret_cast<const char*>(xn);
        const char* srcA = xb + (size_t)cb * 32768;
        const char* srcB = xb + (size_t)rb * 32768;
#pragma unroll
        for (int i = 0; i < 8; ++i) {
            const int p = i * 8192 + t * 16;
            const int pp = p & 32767;
            const int src = pp ^ (((pp >> 8) & 7) << 4);
            __builtin_amdgcn_global_load_lds(
                (const __attribute__((address_space(1))) void*)(
                    (i < 4 ? srcA : srcB) + src),
                (__attribute__((address_space(3))) void*)(lds + p), 16, 0, 0);
        }
    }
    asm volatile("s_waitcnt vmcnt(0)" ::: "memory");
    __syncthreads();

    // ---- MFMA: per wave 64 cols (p) x 32 rows (qq), transposed-tile layout
    f32x4 acc[4][2];
#pragma unroll
    for (int i = 0; i < 4; ++i)
#pragma unroll
        for (int j = 0; j < 2; ++j) {
            f32x4 z = {0.0f, 0.0f, 0.0f, 0.0f};
            acc[i][j] = z;
        }

#pragma unroll
    for (int ks = 0; ks < 4; ++ks) {
        bf16x8 af[4], bfr[2];
#pragma unroll
        for (int p = 0; p < 4; ++p) {
            const int c = wM * 64 + p * 16 + lm16;
            const int v = c * 256 + ks * 64 + lh * 16;
            af[p] = *reinterpret_cast<const bf16x8*>(lds + (v ^ ((c & 7) << 4)));
        }
#pragma unroll
        for (int qq = 0; qq < 2; ++qq) {
            const int r = wN * 32 + qq * 16 + lm16;
            const int v = r * 256 + ks * 64 + lh * 16;
            bfr[qq] = *reinterpret_cast<const bf16x8*>(
                lds + 32768 + (v ^ ((r & 7) << 4)));
        }
#pragma unroll
        for (int p = 0; p < 4; ++p)
#pragma unroll
            for (int qq = 0; qq < 2; ++qq)
                acc[p][qq] = __builtin_amdgcn_mfma_f32_16x16x32_bf16(
                    af[p], bfr[qq], acc[p][qq], 0, 0, 0);
    }

    if (rb == cb)
        epilogue<true>(acc, W0, W1, shbase, wM, wN, lm16, lh, l, Lb);
    else
        epilogue<false>(acc, W0, W1, shbase, wM, wN, lm16, lh, l, Lb);
    __syncthreads();

    // ---- block combine (wM halves) + coalesced 512B stores, [slice][row]
    if (t < 128) {
        const size_t o = (size_t)cb * NN + rb * 128 + t;
        PtT[o] = Lb[0 * 128 + t] + Lb[3 * 128 + t];
        PtA[o] = Lb[1 * 128 + t] + Lb[4 * 128 + t];
        PtY[o] = Lb[2 * 128 + t] + Lb[5 * 128 + t];
    }
}

// ---- kernel 3: per-row slice reduce (coalesced) + loss + mean ----
__global__ __launch_bounds__(256) void finalize_kernel(
    const float* __restrict__ PtT, const float* __restrict__ PtA,
    const float* __restrict__ PtY, const float* __restrict__ Pp,
    float* __restrict__ out) {
    const int t = threadIdx.x;
    const int r = blockIdx.x * 256 + t;  // one row per thread
    float T = 0.0f, A = 0.0f, Y = 0.0f;
#pragma unroll 8
    for (int cb = 0; cb < 64; ++cb) {
        T += PtT[(size_t)cb * NN + r];
        A += PtA[(size_t)cb * NN + r];
        Y += PtY[(size_t)cb * NN + r];
    }
    const float P = Pp[r];
    const float nl = T - Y;
    // diag term: -log1p(nl * e^-20), s_ii = 20 exactly (fp32 cos_ii = 1)
    const float lm =
        (A - (P - 1.0f) * logf(nl) - log1pf(nl * 2.0611536e-9f)) / P;

    __shared__ float red[256];
    red[t] = lm;
    __syncthreads();
    for (int k = 128; k > 0; k >>= 1) {
        if (t < k) red[t] += red[t + k];
        __syncthreads();
    }
    if (t == 0) atomicAdd(out, -red[0] * (1.0f / (float)NN));
}

extern "C" void kernel_launch(void* const* d_in, const int* in_sizes, int n_in,
                              void* d_out, int out_size, void* d_ws,
                              size_t ws_size, hipStream_t stream) {
    const float* x = (const float*)d_in[0];
    const float* y = (const float*)d_in[1];

    char* ws = (char*)d_ws;
    unsigned short* xn = (unsigned short*)ws;      // 2 MB
    u64* bits = (u64*)(ws + (2ull << 20));         // 8 MB
    float* PtT = (float*)(ws + (10ull << 20));     // 2 MB  [slice][row]
    float* PtA = (float*)(ws + (12ull << 20));     // 2 MB
    float* PtY = (float*)(ws + (14ull << 20));     // 2 MB
    float* Pp = (float*)(ws + (16ull << 20));      // 32 KB

    hipMemsetAsync(d_out, 0, sizeof(float), stream);
    prep_kernel<<<4096, 256, 0, stream>>>(x, y, xn, bits, Pp);
    contrast_main_kernel<<<4096, 512, 0, stream>>>(xn, bits, PtT, PtA, PtY);
    finalize_kernel<<<NN / 256, 256, 0, stream>>>(PtT, PtA, PtY, Pp,
                                                  (float*)d_out);
}